// Round 1
// baseline (2289.050 us; speedup 1.0000x reference)
//
#include <hip/hip_runtime.h>
#include <stdint.h>

#define B_DIM 8
#define S_DIM 4096
#define F_DIM 512
#define H_DIM 2048
#define W_DIM 16
#define L_DIM 4081               // S - W + 1
#define M_TOT 32648              // B * L
#define K1_DIM 8192              // W * F
#define SXF 2097152              // S * F

typedef __bf16 bf16x8 __attribute__((ext_vector_type(8)));
typedef float f32x4 __attribute__((ext_vector_type(4)));

__device__ __forceinline__ unsigned short f2bf(float f) {
  union { float f; uint32_t u; } a; a.f = f;
  return (unsigned short)((a.u + 0x7fffu + ((a.u >> 16) & 1u)) >> 16);
}

__device__ __forceinline__ void async16(const void* g, void* l) {
  __builtin_amdgcn_global_load_lds(
      (__attribute__((address_space(1))) void*)(uintptr_t)g,
      (__attribute__((address_space(3))) void*)l, 16, 0, 0);
}

// ---------------- GEMM1: h = relu(x_hankel @ w1 + b1), bf16 in, bf16 out ----
// A: xb (bf16 bits), row m -> base b*SXF + l*F, k contiguous (Hankel trick)
// B: w1t [N1=2048][K1=8192] (k contiguous per row)
// Tile 128x128, BK=32, 4 waves, each wave 64x64 (4x4 of 16x16x32 MFMA).
// LDS in fragment order: chunk c (16B) = ((t*4+g)*16 + m)*16B so consuming
// lane reads at tile_base + lane*16 (ds_read_b128, conflict-free) and
// global_load_lds (uniform base + lane*16) stages it directly.
__global__ __launch_bounds__(256) void gemm1_kernel(
    const unsigned short* __restrict__ xb,
    const unsigned short* __restrict__ w1t,
    const float* __restrict__ bias1,
    unsigned short* __restrict__ h)
{
  __shared__ alignas(16) unsigned short lsA[4096];   // 8 KB
  __shared__ alignas(16) unsigned short lsB[4096];   // 8 KB

  const int tid  = threadIdx.x;
  const int lane = tid & 63;
  const int wave = tid >> 6;
  const int mt = blockIdx.x;
  const int nt = blockIdx.y;

  // staging decode: chunk c0 = tid (m=c&15, g=(c>>4)&3, t=c>>6); c1 = tid+256 (t+=4)
  const int sm = tid & 15;
  const int sg = (tid >> 4) & 3;
  const int st = tid >> 6;

  int row0 = mt * 128 + st * 16 + sm;
  int row1 = row0 + 64;
  if (row0 >= M_TOT) row0 = M_TOT - 1;
  if (row1 >= M_TOT) row1 = M_TOT - 1;
  const int b0 = row0 / L_DIM, l0 = row0 - b0 * L_DIM;
  const int b1r = row1 / L_DIM, l1 = row1 - b1r * L_DIM;
  const unsigned short* pA0 = xb + (size_t)b0  * SXF + (size_t)l0 * F_DIM + sg * 8;
  const unsigned short* pA1 = xb + (size_t)b1r * SXF + (size_t)l1 * F_DIM + sg * 8;

  const int col0 = nt * 128 + st * 16 + sm;
  const unsigned short* pB0 = w1t + (size_t)col0 * K1_DIM + sg * 8;
  const unsigned short* pB1 = pB0 + (size_t)64 * K1_DIM;

  unsigned short* dA0 = lsA + wave * 512;
  unsigned short* dA1 = lsA + 2048 + wave * 512;
  unsigned short* dB0 = lsB + wave * 512;
  unsigned short* dB1 = lsB + 2048 + wave * 512;

  const int wm = wave >> 1, wn = wave & 1;
  const bf16x8* lA = (const bf16x8*)lsA + wm * 256 + lane;
  const bf16x8* lB = (const bf16x8*)lsB + wn * 256 + lane;

  f32x4 acc[4][4] = {};

  for (int kt = 0; kt < K1_DIM / 32; ++kt) {
    async16(pA0, dA0);
    async16(pA1, dA1);
    async16(pB0, dB0);
    async16(pB1, dB1);
    pA0 += 32; pA1 += 32; pB0 += 32; pB1 += 32;
    __syncthreads();
    bf16x8 af[4], bfr[4];
#pragma unroll
    for (int t = 0; t < 4; ++t) af[t] = lA[t * 64];
#pragma unroll
    for (int u = 0; u < 4; ++u) bfr[u] = lB[u * 64];
#pragma unroll
    for (int t = 0; t < 4; ++t)
#pragma unroll
      for (int u = 0; u < 4; ++u)
        acc[t][u] = __builtin_amdgcn_mfma_f32_16x16x32_bf16(af[t], bfr[u], acc[t][u], 0, 0, 0);
    __syncthreads();
  }

  // C/D layout: col = lane&15, row = (lane>>4)*4 + reg
  const int ncol = nt * 128 + wn * 64 + (lane & 15);
  const int mrow = mt * 128 + wm * 64 + (lane >> 4) * 4;
#pragma unroll
  for (int u = 0; u < 4; ++u) {
    const int n = ncol + u * 16;
    const float bv = bias1[n];
#pragma unroll
    for (int t = 0; t < 4; ++t) {
#pragma unroll
      for (int r = 0; r < 4; ++r) {
        const int m = mrow + t * 16 + r;
        if (m < M_TOT) {
          float v = acc[t][u][r] + bv;
          v = v > 0.f ? v : 0.f;
          h[(size_t)m * H_DIM + n] = f2bf(v);
        }
      }
    }
  }
}

// ---------------- GEMM2: y = h @ w2 + b2, fp32 out with Hankel-pad store ----
__global__ __launch_bounds__(256) void gemm2_kernel(
    const unsigned short* __restrict__ hmat,
    const unsigned short* __restrict__ w2t,   // [512][2048]
    const float* __restrict__ bias2,
    float* __restrict__ out)
{
  __shared__ alignas(16) unsigned short lsA[4096];
  __shared__ alignas(16) unsigned short lsB[4096];

  const int tid  = threadIdx.x;
  const int lane = tid & 63;
  const int wave = tid >> 6;
  const int mt = blockIdx.x;
  const int nt = blockIdx.y;

  const int sm = tid & 15;
  const int sg = (tid >> 4) & 3;
  const int st = tid >> 6;

  int row0 = mt * 128 + st * 16 + sm;
  int row1 = row0 + 64;
  if (row0 >= M_TOT) row0 = M_TOT - 1;
  if (row1 >= M_TOT) row1 = M_TOT - 1;
  const unsigned short* pA0 = hmat + (size_t)row0 * H_DIM + sg * 8;
  const unsigned short* pA1 = hmat + (size_t)row1 * H_DIM + sg * 8;

  const int col0 = nt * 128 + st * 16 + sm;
  const unsigned short* pB0 = w2t + (size_t)col0 * H_DIM + sg * 8;
  const unsigned short* pB1 = pB0 + (size_t)64 * H_DIM;

  unsigned short* dA0 = lsA + wave * 512;
  unsigned short* dA1 = lsA + 2048 + wave * 512;
  unsigned short* dB0 = lsB + wave * 512;
  unsigned short* dB1 = lsB + 2048 + wave * 512;

  const int wm = wave >> 1, wn = wave & 1;
  const bf16x8* lA = (const bf16x8*)lsA + wm * 256 + lane;
  const bf16x8* lB = (const bf16x8*)lsB + wn * 256 + lane;

  f32x4 acc[4][4] = {};

  for (int kt = 0; kt < H_DIM / 32; ++kt) {
    async16(pA0, dA0);
    async16(pA1, dA1);
    async16(pB0, dB0);
    async16(pB1, dB1);
    pA0 += 32; pA1 += 32; pB0 += 32; pB1 += 32;
    __syncthreads();
    bf16x8 af[4], bfr[4];
#pragma unroll
    for (int t = 0; t < 4; ++t) af[t] = lA[t * 64];
#pragma unroll
    for (int u = 0; u < 4; ++u) bfr[u] = lB[u * 64];
#pragma unroll
    for (int t = 0; t < 4; ++t)
#pragma unroll
      for (int u = 0; u < 4; ++u)
        acc[t][u] = __builtin_amdgcn_mfma_f32_16x16x32_bf16(af[t], bfr[u], acc[t][u], 0, 0, 0);
    __syncthreads();
  }

  const int ncol = nt * 128 + wn * 64 + (lane & 15);
  const int mrow = mt * 128 + wm * 64 + (lane >> 4) * 4;
#pragma unroll
  for (int u = 0; u < 4; ++u) {
    const int n = ncol + u * 16;
    const float bv = bias2[n];
#pragma unroll
    for (int t = 0; t < 4; ++t) {
#pragma unroll
      for (int r = 0; r < 4; ++r) {
        const int m = mrow + t * 16 + r;
        if (m < M_TOT) {
          const int b = m / L_DIM;
          const int l = m - b * L_DIM;
          out[(size_t)b * SXF + (size_t)l * F_DIM + n] = acc[t][u][r] + bv;
        }
      }
    }
  }
}

// ---------------- conversion / transpose / pad helpers ----------------------
__global__ void cvt_bf16_kernel(const float* __restrict__ in,
                                unsigned short* __restrict__ out, int n4) {
  int idx = blockIdx.x * 256 + threadIdx.x;
  if (idx < n4) {
    float4 v = ((const float4*)in)[idx];
    ushort4 o;
    o.x = f2bf(v.x); o.y = f2bf(v.y); o.z = f2bf(v.z); o.w = f2bf(v.w);
    ((ushort4*)out)[idx] = o;
  }
}

// out[c][r] = bf16(in[r][c]); R, C multiples of 64
__global__ void transpose_cvt_kernel(const float* __restrict__ in,
                                     unsigned short* __restrict__ out, int R, int C) {
  __shared__ unsigned short tile[64][72];
  const int tx = threadIdx.x & 15;
  const int ty = threadIdx.x >> 4;
  const int r0 = blockIdx.x * 64;
  const int c0 = blockIdx.y * 64;
#pragma unroll
  for (int i = 0; i < 4; ++i) {
    const int r = r0 + ty + i * 16;
    float4 v = *(const float4*)(in + (size_t)r * C + c0 + tx * 4);
    tile[ty + i * 16][tx * 4 + 0] = f2bf(v.x);
    tile[ty + i * 16][tx * 4 + 1] = f2bf(v.y);
    tile[ty + i * 16][tx * 4 + 2] = f2bf(v.z);
    tile[ty + i * 16][tx * 4 + 3] = f2bf(v.w);
  }
  __syncthreads();
#pragma unroll
  for (int i = 0; i < 4; ++i) {
    const int c = c0 + ty + i * 16;
    ushort4 o;
    o.x = tile[tx * 4 + 0][ty + i * 16];
    o.y = tile[tx * 4 + 1][ty + i * 16];
    o.z = tile[tx * 4 + 2][ty + i * 16];
    o.w = tile[tx * 4 + 3][ty + i * 16];
    *(ushort4*)(out + (size_t)c * R + r0 + tx * 4) = o;
  }
}

__global__ void zero_pad_kernel(float* __restrict__ out) {
  int idx = blockIdx.x * 256 + threadIdx.x;          // 8 * 15 * 128 float4s
  if (idx < B_DIM * 15 * 128) {
    int b = idx / (15 * 128);
    int rem = idx - b * (15 * 128);
    int l = L_DIM + rem / 128;
    int f4 = rem - (rem / 128) * 128;
    ((float4*)out)[(size_t)b * (SXF / 4) + (size_t)l * 128 + f4] =
        make_float4(0.f, 0.f, 0.f, 0.f);
  }
}

__global__ void fill_sentinel(float* out, int n) {   // distinctive ws-too-small marker
  int idx = blockIdx.x * 256 + threadIdx.x;
  if (idx < n) out[idx] = 12345.0f;
}

extern "C" void kernel_launch(void* const* d_in, const int* in_sizes, int n_in,
                              void* d_out, int out_size, void* d_ws, size_t ws_size,
                              hipStream_t stream) {
  const float* x  = (const float*)d_in[0];
  const float* w1 = (const float*)d_in[1];
  const float* b1 = (const float*)d_in[2];
  const float* w2 = (const float*)d_in[3];
  const float* b2 = (const float*)d_in[4];
  float* out = (float*)d_out;

  const size_t OFF_H   = 0;                               // 32648*2048*2 = 133726208
  const size_t OFF_XB  = 133726208;                       // 16777216*2   = 33554432
  const size_t OFF_W1T = OFF_XB + 33554432;               // 8192*2048*2  = 33554432
  const size_t OFF_W2T = OFF_W1T + 33554432;              // 2048*512*2   = 2097152
  const size_t WS_NEED = OFF_W2T + 2097152;               // ~202.9 MB

  if (ws_size < WS_NEED) {
    fill_sentinel<<<65536, 256, 0, stream>>>(out, out_size);
    return;
  }

  unsigned short* hbuf = (unsigned short*)((char*)d_ws + OFF_H);
  unsigned short* xb   = (unsigned short*)((char*)d_ws + OFF_XB);
  unsigned short* w1t  = (unsigned short*)((char*)d_ws + OFF_W1T);
  unsigned short* w2t  = (unsigned short*)((char*)d_ws + OFF_W2T);

  cvt_bf16_kernel<<<16384, 256, 0, stream>>>(x, xb, 4194304);
  transpose_cvt_kernel<<<dim3(128, 32), 256, 0, stream>>>(w1, w1t, 8192, 2048);
  transpose_cvt_kernel<<<dim3(32, 8), 256, 0, stream>>>(w2, w2t, 2048, 512);
  gemm1_kernel<<<dim3(256, 16), 256, 0, stream>>>(xb, w1t, b1, hbuf);
  gemm2_kernel<<<dim3(256, 4), 256, 0, stream>>>(hbuf, w2t, b2, out);
  zero_pad_kernel<<<60, 256, 0, stream>>>(out);
}